// Round 8
// baseline (551.561 us; speedup 1.0000x reference)
//
#include <hip/hip_runtime.h>
#include <hip/hip_bf16.h>

#define NN 100000
#define EE 1600000
#define HH 128
#define GG 64
#define LL 3
#define BN_EPS 1e-5f
#define NT 391              // ceil(NN/256): 256-node tiles
#define CAP 6144            // slab capacity/tile (avg 4092, +6 sigma ~4500)

typedef __hip_bfloat16 bf16;
typedef __attribute__((ext_vector_type(8))) short short8;
typedef __attribute__((ext_vector_type(4))) float floatx4;

__device__ __forceinline__ float lo16(unsigned v) { return __uint_as_float(v << 16); }
__device__ __forceinline__ float hi16(unsigned v) { return __uint_as_float(v & 0xffff0000u); }
__device__ __forceinline__ unsigned short f2b(float v) {
    bf16 h = __float2bfloat16(v);
    return *(unsigned short*)&h;
}
__device__ __forceinline__ unsigned pack2(float a, float b) {
    return (unsigned)f2b(a) | ((unsigned)f2b(b) << 16);
}
__device__ __forceinline__ int geti(const int* __restrict__ p, int i, int f) {
    return f ? p[2 * i] : p[i];
}

// ---- pass 1: deg count + tile partition into slabs (+int-width detect) ---
__global__ __launch_bounds__(256) void k_part(const int* __restrict__ ei,
        int* __restrict__ cnt, int* __restrict__ tcur,
        unsigned* __restrict__ slab, int* __restrict__ flag) {
    __shared__ int lcnt[NT], lbase[NT], gbase[NT];
    __shared__ int sd[512];
    __shared__ uint2 sorted[4096];
    int t = threadIdx.x;
    int e0 = blockIdx.x * 4096;
    // int64 layout <=> odd int32 slots all zero over a 64-edge probe
    int probe = ei[2 * (e0 + (t & 63)) + 1];
    int f = __any(probe != 0) ? 0 : 1;
    if (blockIdx.x == 0 && t == 0) *flag = f;
    int nume = EE - e0 < 4096 ? EE - e0 : 4096;
    for (int i = t; i < NT; i += 256) lcnt[i] = 0;
    __syncthreads();
    uint2 ed[16]; int myloc[16], mytile[16];
#pragma unroll
    for (int i = 0; i < 16; i++) {
        int li = i * 256 + t;
        if (li < nume) {
            int e = e0 + li;
            int src = geti(ei, e, f), dst = geti(ei, EE + e, f);
            ed[i] = make_uint2((unsigned)src, (unsigned)dst);
            mytile[i] = dst >> 8;
            myloc[i] = atomicAdd(&lcnt[mytile[i]], 1);
            atomicAdd(&cnt[dst], 1);               // global degree
        }
    }
    __syncthreads();
    int own0 = t < NT ? lcnt[t] : 0;
    int own1 = t + 256 < NT ? lcnt[t + 256] : 0;
    sd[t] = own0; sd[t + 256] = own1;
    __syncthreads();
    for (int off = 1; off < 512; off <<= 1) {
        int a = t >= off ? sd[t - off] : 0;
        int b = t + 256 >= off ? sd[t + 256 - off] : 0;
        __syncthreads();
        sd[t] += a; sd[t + 256] += b;
        __syncthreads();
    }
    if (t < NT) {
        lbase[t] = sd[t] - own0;
        gbase[t] = own0 > 0 ? atomicAdd(&tcur[t], own0) : 0;
    }
    if (t + 256 < NT) {
        lbase[t + 256] = sd[t + 256] - own1;
        gbase[t + 256] = own1 > 0 ? atomicAdd(&tcur[t + 256], own1) : 0;
    }
    __syncthreads();
#pragma unroll
    for (int i = 0; i < 16; i++) {
        int li = i * 256 + t;
        if (li < nume) sorted[lbase[mytile[i]] + myloc[i]] = ed[i];
    }
    __syncthreads();
    for (int idx = t; idx < nume; idx += 256) {
        uint2 e = sorted[idx];
        int tile = (int)(e.y >> 8);
        int pos = gbase[tile] + (idx - lbase[tile]);
        if (pos < CAP)                             // safety (never in practice)
            slab[(size_t)tile * CAP + pos] = (e.x << 8) | (e.y & 255u);
    }
}

// ---- pass 2: per-tile CSR-in-slab, direct ewp emit, offs/dinv ------------
__global__ __launch_bounds__(256) void k_csr(const unsigned* __restrict__ slab,
        const int* __restrict__ tcur, const int* __restrict__ cnt,
        unsigned* __restrict__ ewp, int* __restrict__ offs,
        float* __restrict__ dinv) {
    __shared__ int hist[256], exs[256], cur[256];
    __shared__ unsigned outb[CAP];
    int T = blockIdx.x, t = threadIdx.x;
    int ne = tcur[T];
    if (ne > CAP) ne = CAP;
    const unsigned* sl = slab + (size_t)T * CAP;
    hist[t] = 0;
    __syncthreads();
    for (int i = t; i < ne; i += 256)
        atomicAdd(&hist[__builtin_nontemporal_load(&sl[i]) & 255u], 1);
    __syncthreads();
    int c = hist[t];
    exs[t] = c;
    __syncthreads();
    for (int off = 1; off < 256; off <<= 1) {
        int a = t >= off ? exs[t - off] : 0;
        __syncthreads();
        exs[t] += a;
        __syncthreads();
    }
    int ex = exs[t] - c;
    cur[t] = ex;
    int node = T * 256 + t;
    if (node < NN) {
        offs[node] = T * CAP + ex;
        dinv[node] = rsqrtf(1.0f + (float)c);
    }
    __syncthreads();
    for (int i = t; i < ne; i += 256) {
        unsigned p = __builtin_nontemporal_load(&sl[i]);
        unsigned s = p >> 8;
        int q = atomicAdd(&cur[p & 255u], 1);
        float w = rsqrtf(1.0f + (float)cnt[s]);    // dinv[src] on the fly
        outb[q] = (s << 15) | ((unsigned)f2b(w) & 0x7fffu);
    }
    __syncthreads();
    for (int i = t; i < ne; i += 256)
        ewp[(size_t)T * CAP + i] = outb[i];
}

// ---- small prep: weight casts + BN fold + pool init ----------------------
__global__ void k_prep(const float* __restrict__ conv_w,
        const float* __restrict__ nw1, unsigned short* __restrict__ cwB,
        unsigned short* __restrict__ n1B, float* __restrict__ bnA,
        float* __restrict__ bnB, const float* __restrict__ conv_b,
        const float* __restrict__ g, const float* __restrict__ be,
        const float* __restrict__ mn, const float* __restrict__ vr,
        float* __restrict__ gsum, float* __restrict__ gcnt) {
    int i = blockIdx.x * 256 + threadIdx.x;
    if (i < LL * HH * HH) cwB[i] = f2b(conv_w[i]);
    if (i < 64 * HH) n1B[i] = f2b(nw1[i]);
    if (i < LL * HH) {
        float A = g[i] * rsqrtf(vr[i] + BN_EPS);
        bnA[i] = A;
        bnB[i] = (conv_b[i] - mn[i]) * A + be[i];
    }
    if (i < GG * HH) gsum[i] = 0.f;
    if (i < GG) gcnt[i] = 0.f;
}

// ---- MFMA bf16 GEMM: out[r][c] = sum_k in[r][k]*W[c][k] (+bias, relu) ----
// FUSE: fold y2 = y1 @ w2^T + b2 (64->2) into the epilogue (node head).
template<typename AT, int NC, bool FUSE>
__global__ __launch_bounds__(256) void k_gemm(const AT* __restrict__ in,
        const unsigned short* __restrict__ Wb, const float* __restrict__ bias,
        unsigned short* __restrict__ outh, int do_relu,
        const float* __restrict__ w2, const float* __restrict__ b2v,
        float* __restrict__ out2f) {
    int wave = threadIdx.x >> 6, lane = threadIdx.x & 63;
    int ln = lane & 15, q = lane >> 4;
    int r0 = blockIdx.x * 64 + wave * 16;
    int row = r0 + ln;
    int rr = row < NN ? row : NN - 1;          // clamp loads, guard stores
    short8 a[4];
    if constexpr (sizeof(AT) == 2) {
        const short8* ap = (const short8*)(in + (size_t)rr * HH);
#pragma unroll
        for (int kt = 0; kt < 4; kt++) a[kt] = ap[kt * 4 + q];
    } else {
        const float4* ap = (const float4*)(in + (size_t)rr * HH);
#pragma unroll
        for (int kt = 0; kt < 4; kt++) {
            float4 f0 = ap[(kt * 4 + q) * 2];
            float4 f1 = ap[(kt * 4 + q) * 2 + 1];
            a[kt][0] = (short)f2b(f0.x); a[kt][1] = (short)f2b(f0.y);
            a[kt][2] = (short)f2b(f0.z); a[kt][3] = (short)f2b(f0.w);
            a[kt][4] = (short)f2b(f1.x); a[kt][5] = (short)f2b(f1.y);
            a[kt][6] = (short)f2b(f1.z); a[kt][7] = (short)f2b(f1.w);
        }
    }
    float p0[4], p1[4];
    if constexpr (FUSE) {
#pragma unroll
        for (int r = 0; r < 4; r++) { p0[r] = 0.f; p1[r] = 0.f; }
    }
#pragma unroll
    for (int ct = 0; ct < NC / 16; ct++) {
        int c = ct * 16 + ln;
        const short8* bp = (const short8*)(Wb + (size_t)c * HH);
        floatx4 acc = {0.f, 0.f, 0.f, 0.f};
#pragma unroll
        for (int kt = 0; kt < 4; kt++) {
            short8 b = bp[kt * 4 + q];
            acc = __builtin_amdgcn_mfma_f32_16x16x32_bf16(a[kt], b, acc, 0, 0, 0);
        }
        float bv = bias ? bias[c] : 0.f;
        if constexpr (FUSE) {
            float wa = w2[c], wb = w2[64 + c];
#pragma unroll
            for (int reg = 0; reg < 4; reg++) {
                float v = fmaxf(acc[reg] + bv, 0.f);   // y1 with bias+relu
                p0[reg] = fmaf(v, wa, p0[reg]);
                p1[reg] = fmaf(v, wb, p1[reg]);
            }
        } else {
#pragma unroll
            for (int reg = 0; reg < 4; reg++) {
                int orow = r0 + q * 4 + reg;   // C/D: col=lane&15, row=quad*4+reg
                if (orow < NN) {
                    float v = acc[reg] + bv;
                    if (do_relu) v = fmaxf(v, 0.f);
                    outh[(size_t)orow * NC + c] = f2b(v);
                }
            }
        }
    }
    if constexpr (FUSE) {
#pragma unroll
        for (int off = 1; off < 16; off <<= 1) {
#pragma unroll
            for (int r = 0; r < 4; r++) {
                p0[r] += __shfl_xor(p0[r], off);
                p1[r] += __shfl_xor(p1[r], off);
            }
        }
        if (ln == 0) {
            float ba = b2v[0], bb = b2v[1];
#pragma unroll
            for (int reg = 0; reg < 4; reg++) {
                int orow = r0 + q * 4 + reg;
                if (orow < NN)
                    ((float2*)out2f)[orow] = make_float2(p0[reg] + ba, p1[reg] + bb);
            }
        }
    }
}

// ---- fused gather segment-reduce + self-loop + BN + ReLU -----------------
// one wave per node; lanes split 32/32 over 2 edges (uint2 = 4 ch/lane);
// 4B packed meta via nontemporal load, shfl broadcast, depth-8 pipeline.
__global__ __launch_bounds__(256) void k_aggr(const uint2* __restrict__ tH2,
        const unsigned* __restrict__ ewp, const int* __restrict__ offs,
        const int* __restrict__ cnt, const float* __restrict__ dinv,
        const float* __restrict__ bnA, const float* __restrict__ bnB,
        uint2* __restrict__ hout) {
    int wave = threadIdx.x >> 6, lane = threadIdx.x & 63;
    int node = blockIdx.x * 4 + wave;
    if (node >= NN) return;
    int base = offs[node], ne = cnt[node];
    float dd = dinv[node];
    int half = lane >> 5, li = lane & 31;
    uint2 sv = tH2[(size_t)node * 32 + li];
    float ws = half ? 0.f : dd;                // self = virtual edge, half 0
    float4 acc;
    acc.x = lo16(sv.x) * ws; acc.y = hi16(sv.x) * ws;
    acc.z = lo16(sv.y) * ws; acc.w = hi16(sv.y) * ws;
    for (int k0 = 0; k0 < ne; k0 += 64) {
        int idx = k0 + lane;
        unsigned m = idx < ne ? __builtin_nontemporal_load(&ewp[base + idx]) : 0u;
        int c2 = ne - k0 < 64 ? ne - k0 : 64;
        for (int kk = 0; kk < c2; kk += 16) {
            uint2 vv[8]; float wj[8];
#pragma unroll
            for (int j = 0; j < 8; j++) {
                int e = kk + 2 * j + half;
                unsigned mm = (unsigned)__shfl((int)m, e);
                int s = (int)(mm >> 15);
                wj[j] = __uint_as_float((mm & 0x7fffu) << 16);
                vv[j] = tH2[(size_t)s * 32 + li];
            }
#pragma unroll
            for (int j = 0; j < 8; j++) {
                acc.x = fmaf(lo16(vv[j].x), wj[j], acc.x);
                acc.y = fmaf(hi16(vv[j].x), wj[j], acc.y);
                acc.z = fmaf(lo16(vv[j].y), wj[j], acc.z);
                acc.w = fmaf(hi16(vv[j].y), wj[j], acc.w);
            }
        }
    }
    acc.x += __shfl_xor(acc.x, 32);
    acc.y += __shfl_xor(acc.y, 32);
    acc.z += __shfl_xor(acc.z, 32);
    acc.w += __shfl_xor(acc.w, 32);
    if (half == 0) {
        float4 Av = ((const float4*)bnA)[li];
        float4 Bv = ((const float4*)bnB)[li];
        float r0 = fmaxf(fmaf(acc.x * dd, Av.x, Bv.x), 0.f);
        float r1 = fmaxf(fmaf(acc.y * dd, Av.y, Bv.y), 0.f);
        float r2 = fmaxf(fmaf(acc.z * dd, Av.z, Bv.z), 0.f);
        float r3 = fmaxf(fmaf(acc.w * dd, Av.w, Bv.w), 0.f);
        unsigned long long v64 =
            ((unsigned long long)pack2(r2, r3) << 32) | pack2(r0, r1);
        __builtin_nontemporal_store(v64,
            (unsigned long long*)&hout[(size_t)node * 32 + li]);
    }
}

// ---- graph pooling: 1 wave per 32-node chunk, run-flush atomics ----------
#define PN 32
__global__ __launch_bounds__(64) void k_pool(const unsigned* __restrict__ hb,
        const int* __restrict__ batch, float* __restrict__ gsum,
        float* __restrict__ gcnt, const int* __restrict__ flag) {
    int lane = threadIdx.x;
    int f = *flag;
    int s0 = blockIdx.x * PN;
    int e0 = s0 + PN < NN ? s0 + PN : NN;
    int cur = geti(batch, s0, f);
    float a0 = 0.f, a1 = 0.f, cn = 0.f;
    for (int n = s0; n < e0; n++) {
        int g = geti(batch, n, f);
        if (g != cur) {                        // wave-uniform branch
            atomicAdd(&gsum[cur * HH + 2 * lane], a0);
            atomicAdd(&gsum[cur * HH + 2 * lane + 1], a1);
            if (lane == 0) atomicAdd(&gcnt[cur], cn);
            a0 = a1 = cn = 0.f; cur = g;
        }
        unsigned v = hb[(size_t)n * 64 + lane];
        a0 += lo16(v); a1 += hi16(v); cn += 1.f;
    }
    atomicAdd(&gsum[cur * HH + 2 * lane], a0);
    atomicAdd(&gsum[cur * HH + 2 * lane + 1], a1);
    if (lane == 0) atomicAdd(&gcnt[cur], cn);
}

// ---- graph head: one block per graph -------------------------------------
__global__ __launch_bounds__(64) void k_ghead(const float* __restrict__ gsum,
        const float* __restrict__ gcnt, const float* __restrict__ w1,
        const float* __restrict__ b1, const float* __restrict__ w2,
        const float* __restrict__ b2v, float* __restrict__ out) {
    __shared__ float emb[HH];
    int g = blockIdx.x, lane = threadIdx.x;
    float cn = gcnt[g];
    cn = cn > 1.f ? cn : 1.f;
    float inv = 1.f / cn;
    emb[lane] = gsum[g * HH + lane] * inv;
    emb[lane + 64] = gsum[g * HH + 64 + lane] * inv;
    __syncthreads();
    float acc = b1[lane];
    for (int k = 0; k < HH; k++) acc = fmaf(emb[k], w1[lane * HH + k], acc);
    float y = fmaxf(acc, 0.f);
    float v0 = y * w2[lane];
    float v1 = y * w2[64 + lane];
#pragma unroll
    for (int off = 32; off; off >>= 1) {
        v0 += __shfl_xor(v0, off);
        v1 += __shfl_xor(v1, off);
    }
    if (lane == 0) {
        out[(size_t)NN * 2 + g * 2]     = v0 + b2v[0];
        out[(size_t)NN * 2 + g * 2 + 1] = v1 + b2v[1];
    }
}

extern "C" void kernel_launch(void* const* d_in, const int* in_sizes, int n_in,
                              void* d_out, int out_size, void* d_ws, size_t ws_size,
                              hipStream_t stream) {
    const float* x      = (const float*)d_in[0];
    const int*   ei     = (const int*)d_in[1];
    const int*   batch  = (const int*)d_in[2];
    const float* conv_w = (const float*)d_in[3];
    const float* conv_b = (const float*)d_in[4];
    const float* bn_g   = (const float*)d_in[5];
    const float* bn_b   = (const float*)d_in[6];
    const float* bn_m   = (const float*)d_in[7];
    const float* bn_v   = (const float*)d_in[8];
    const float* nw1    = (const float*)d_in[9];
    const float* nb1    = (const float*)d_in[10];
    const float* nw2    = (const float*)d_in[11];
    const float* nb2    = (const float*)d_in[12];
    const float* gw1    = (const float*)d_in[13];
    const float* gb1    = (const float*)d_in[14];
    const float* gw2    = (const float*)d_in[15];
    const float* gb2    = (const float*)d_in[16];
    float* out = (float*)d_out;

    char* ws = (char*)d_ws;
    size_t off = 0;
    auto alloc = [&](size_t bytes) -> void* {
        void* p = ws + off;
        off += (bytes + 255) & ~(size_t)255;
        return p;
    };
    unsigned short* hb   = (unsigned short*)alloc((size_t)NN * HH * 2); // bf16 h
    unsigned short* tb   = (unsigned short*)alloc((size_t)NN * HH * 2); // bf16 t
    unsigned* slab   = (unsigned*)alloc((size_t)NT * CAP * 4);  // 9.6 MB
    unsigned* ewp    = (unsigned*)alloc((size_t)NT * CAP * 4);  // 9.6 MB
    int*      cnt    = (int*)     alloc((size_t)(NN + NT) * 4); // cnt + tcur
    int*      tcur   = cnt + NN;
    int*      offs   = (int*)     alloc((size_t)NN * 4);
    float*    dinv   = (float*)   alloc((size_t)NN * 4);
    float*    bnA    = (float*)   alloc((size_t)LL * HH * 4);
    float*    bnB    = (float*)   alloc((size_t)LL * HH * 4);
    float*    gsum   = (float*)   alloc((size_t)GG * HH * 4);
    float*    gcnt   = (float*)   alloc((size_t)GG * 4);
    unsigned short* cwB = (unsigned short*)alloc((size_t)LL * HH * HH * 2);
    unsigned short* n1B = (unsigned short*)alloc((size_t)64 * HH * 2);
    int*      flag   = (int*)     alloc(256);

    // CSR build: single partition pass -> per-tile sort (direct ewp emit)
    hipMemsetAsync(cnt, 0, (size_t)(NN + NT) * 4, stream);
    k_part<<<(EE + 4095) / 4096, 256, 0, stream>>>(ei, cnt, tcur, slab, flag);
    k_csr<<<NT, 256, 0, stream>>>(slab, tcur, cnt, ewp, offs, dinv);
    k_prep<<<(LL * HH * HH + 255) / 256, 256, 0, stream>>>(conv_w, nw1, cwB, n1B,
            bnA, bnB, conv_b, bn_g, bn_b, bn_m, bn_v, gsum, gcnt);

    // 3 GCN layers: MFMA gemm (h -> bf16 t), fused aggr+BN+ReLU (t -> bf16 h)
    k_gemm<float, HH, false><<<(NN + 63) / 64, 256, 0, stream>>>(
        x, cwB, nullptr, tb, 0, nullptr, nullptr, nullptr);
    k_aggr<<<(NN + 3) / 4, 256, 0, stream>>>((const uint2*)tb, ewp, offs, cnt,
                                             dinv, bnA, bnB, (uint2*)hb);
    for (int l = 1; l < LL; l++) {
        k_gemm<unsigned short, HH, false><<<(NN + 63) / 64, 256, 0, stream>>>(
            hb, cwB + (size_t)l * HH * HH, nullptr, tb, 0, nullptr, nullptr, nullptr);
        k_aggr<<<(NN + 3) / 4, 256, 0, stream>>>((const uint2*)tb, ewp, offs, cnt,
                                                 dinv, bnA + l * HH, bnB + l * HH,
                                                 (uint2*)hb);
    }

    // node head fully fused: y2 = relu(h@nw1^T+b1)@nw2^T+b2 in one kernel
    k_gemm<unsigned short, 64, true><<<(NN + 63) / 64, 256, 0, stream>>>(
        hb, n1B, nb1, nullptr, 1, nw2, nb2, out);

    // graph head
    k_pool<<<(NN + PN - 1) / PN, 64, 0, stream>>>((const unsigned*)hb, batch,
                                                  gsum, gcnt, flag);
    k_ghead<<<GG, 64, 0, stream>>>(gsum, gcnt, gw1, gb1, gw2, gb2, out);
}

// Round 9
// 544.000 us; speedup vs baseline: 1.0139x; 1.0139x over previous
//
#include <hip/hip_runtime.h>
#include <hip/hip_bf16.h>

#define NN 100000
#define EE 1600000
#define HH 128
#define GG 64
#define LL 3
#define BN_EPS 1e-5f
#define NT 391              // ceil(NN/256): 256-node tiles
#define CAP 6144            // slab capacity/tile (avg 4092, +6 sigma ~4500)

typedef __hip_bfloat16 bf16;
typedef __attribute__((ext_vector_type(8))) short short8;
typedef __attribute__((ext_vector_type(4))) float floatx4;

__device__ __forceinline__ float lo16(unsigned v) { return __uint_as_float(v << 16); }
__device__ __forceinline__ float hi16(unsigned v) { return __uint_as_float(v & 0xffff0000u); }
__device__ __forceinline__ unsigned short f2b(float v) {
    bf16 h = __float2bfloat16(v);
    return *(unsigned short*)&h;
}
__device__ __forceinline__ unsigned pack2(float a, float b) {
    return (unsigned)f2b(a) | ((unsigned)f2b(b) << 16);
}
__device__ __forceinline__ int geti(const int* __restrict__ p, int i, int f) {
    return f ? p[2 * i] : p[i];
}

// ---- pass 1: deg count + tile partition into slabs (+int-width detect) ---
// 1024 threads/block: 16 waves to hide atomic latency (R8 had 4 -> starved)
__global__ __launch_bounds__(1024) void k_part(const int* __restrict__ ei,
        int* __restrict__ cnt, int* __restrict__ tcur,
        unsigned* __restrict__ slab, int* __restrict__ flag) {
    __shared__ int lcnt[NT], lbase[NT], gbase[NT];
    __shared__ int sd[512];
    __shared__ uint2 sorted[4096];
    int t = threadIdx.x;
    int e0 = blockIdx.x * 4096;
    // int64 layout <=> odd int32 slots all zero over a 64-edge probe
    int probe = ei[2 * (e0 + (t & 63)) + 1];
    int f = __any(probe != 0) ? 0 : 1;
    if (blockIdx.x == 0 && t == 0) *flag = f;
    int nume = EE - e0 < 4096 ? EE - e0 : 4096;
    for (int i = t; i < NT; i += 1024) lcnt[i] = 0;
    __syncthreads();
    uint2 ed[4]; int myloc[4], mytile[4];
#pragma unroll
    for (int i = 0; i < 4; i++) {
        int li = i * 1024 + t;
        if (li < nume) {
            int e = e0 + li;
            int src = geti(ei, e, f), dst = geti(ei, EE + e, f);
            ed[i] = make_uint2((unsigned)src, (unsigned)dst);
            mytile[i] = dst >> 8;
            myloc[i] = atomicAdd(&lcnt[mytile[i]], 1);
            atomicAdd(&cnt[dst], 1);               // global degree (no return)
        }
    }
    __syncthreads();
    int own = 0;
    if (t < 512) {
        own = t < NT ? lcnt[t] : 0;
        sd[t] = own;
    }
    __syncthreads();
    for (int off = 1; off < 512; off <<= 1) {
        int y = 0;
        if (t < 512 && t >= off) y = sd[t - off];
        __syncthreads();
        if (t < 512) sd[t] += y;
        __syncthreads();
    }
    if (t < NT) {
        lbase[t] = sd[t] - own;
        gbase[t] = own > 0 ? atomicAdd(&tcur[t], own) : 0;
    }
    __syncthreads();
#pragma unroll
    for (int i = 0; i < 4; i++) {
        int li = i * 1024 + t;
        if (li < nume) sorted[lbase[mytile[i]] + myloc[i]] = ed[i];
    }
    __syncthreads();
    for (int idx = t; idx < nume; idx += 1024) {
        uint2 e = sorted[idx];
        int tile = (int)(e.y >> 8);
        int pos = gbase[tile] + (idx - lbase[tile]);
        if (pos < CAP)                             // safety (never in practice)
            slab[(size_t)tile * CAP + pos] = (e.x << 8) | (e.y & 255u);
    }
}

// ---- pass 2: per-tile CSR-in-slab, direct ewp emit, offs/dinv ------------
__global__ __launch_bounds__(1024) void k_csr(const unsigned* __restrict__ slab,
        const int* __restrict__ tcur, const int* __restrict__ cnt,
        unsigned* __restrict__ ewp, int* __restrict__ offs,
        float* __restrict__ dinv) {
    __shared__ int hist[256], exs[256], cur[256];
    __shared__ unsigned outb[CAP];
    int T = blockIdx.x, t = threadIdx.x;
    int ne = tcur[T];
    if (ne > CAP) ne = CAP;
    const unsigned* sl = slab + (size_t)T * CAP;
    if (t < 256) hist[t] = 0;
    __syncthreads();
    for (int i = t; i < ne; i += 1024)
        atomicAdd(&hist[__builtin_nontemporal_load(&sl[i]) & 255u], 1);
    __syncthreads();
    int c = 0;
    if (t < 256) {
        c = hist[t];
        exs[t] = c;
    }
    __syncthreads();
    for (int off = 1; off < 256; off <<= 1) {
        int a = 0;
        if (t < 256 && t >= off) a = exs[t - off];
        __syncthreads();
        if (t < 256) exs[t] += a;
        __syncthreads();
    }
    if (t < 256) {
        int ex = exs[t] - c;
        cur[t] = ex;
        int node = T * 256 + t;
        if (node < NN) {
            offs[node] = T * CAP + ex;
            dinv[node] = rsqrtf(1.0f + (float)c);
        }
    }
    __syncthreads();
    for (int i = t; i < ne; i += 1024) {
        unsigned p = __builtin_nontemporal_load(&sl[i]);
        unsigned s = p >> 8;
        int q = atomicAdd(&cur[p & 255u], 1);
        float w = rsqrtf(1.0f + (float)cnt[s]);    // dinv[src] on the fly
        outb[q] = (s << 15) | ((unsigned)f2b(w) & 0x7fffu);
    }
    __syncthreads();
    for (int i = t; i < ne; i += 1024)
        ewp[(size_t)T * CAP + i] = outb[i];
}

// ---- small prep: weight casts + BN fold + pool init ----------------------
__global__ void k_prep(const float* __restrict__ conv_w,
        const float* __restrict__ nw1, unsigned short* __restrict__ cwB,
        unsigned short* __restrict__ n1B, float* __restrict__ bnA,
        float* __restrict__ bnB, const float* __restrict__ conv_b,
        const float* __restrict__ g, const float* __restrict__ be,
        const float* __restrict__ mn, const float* __restrict__ vr,
        float* __restrict__ gsum, float* __restrict__ gcnt) {
    int i = blockIdx.x * 256 + threadIdx.x;
    if (i < LL * HH * HH) cwB[i] = f2b(conv_w[i]);
    if (i < 64 * HH) n1B[i] = f2b(nw1[i]);
    if (i < LL * HH) {
        float A = g[i] * rsqrtf(vr[i] + BN_EPS);
        bnA[i] = A;
        bnB[i] = (conv_b[i] - mn[i]) * A + be[i];
    }
    if (i < GG * HH) gsum[i] = 0.f;
    if (i < GG) gcnt[i] = 0.f;
}

// ---- MFMA bf16 GEMM: out[r][c] = sum_k in[r][k]*W[c][k] (+bias, relu) ----
// FUSE: fold y2 = y1 @ w2^T + b2 (64->2) into the epilogue (node head).
template<typename AT, int NC, bool FUSE>
__global__ __launch_bounds__(256) void k_gemm(const AT* __restrict__ in,
        const unsigned short* __restrict__ Wb, const float* __restrict__ bias,
        unsigned short* __restrict__ outh, int do_relu,
        const float* __restrict__ w2, const float* __restrict__ b2v,
        float* __restrict__ out2f) {
    int wave = threadIdx.x >> 6, lane = threadIdx.x & 63;
    int ln = lane & 15, q = lane >> 4;
    int r0 = blockIdx.x * 64 + wave * 16;
    int row = r0 + ln;
    int rr = row < NN ? row : NN - 1;          // clamp loads, guard stores
    short8 a[4];
    if constexpr (sizeof(AT) == 2) {
        const short8* ap = (const short8*)(in + (size_t)rr * HH);
#pragma unroll
        for (int kt = 0; kt < 4; kt++) a[kt] = ap[kt * 4 + q];
    } else {
        const float4* ap = (const float4*)(in + (size_t)rr * HH);
#pragma unroll
        for (int kt = 0; kt < 4; kt++) {
            float4 f0 = ap[(kt * 4 + q) * 2];
            float4 f1 = ap[(kt * 4 + q) * 2 + 1];
            a[kt][0] = (short)f2b(f0.x); a[kt][1] = (short)f2b(f0.y);
            a[kt][2] = (short)f2b(f0.z); a[kt][3] = (short)f2b(f0.w);
            a[kt][4] = (short)f2b(f1.x); a[kt][5] = (short)f2b(f1.y);
            a[kt][6] = (short)f2b(f1.z); a[kt][7] = (short)f2b(f1.w);
        }
    }
    float p0[4], p1[4];
    if constexpr (FUSE) {
#pragma unroll
        for (int r = 0; r < 4; r++) { p0[r] = 0.f; p1[r] = 0.f; }
    }
#pragma unroll
    for (int ct = 0; ct < NC / 16; ct++) {
        int c = ct * 16 + ln;
        const short8* bp = (const short8*)(Wb + (size_t)c * HH);
        floatx4 acc = {0.f, 0.f, 0.f, 0.f};
#pragma unroll
        for (int kt = 0; kt < 4; kt++) {
            short8 b = bp[kt * 4 + q];
            acc = __builtin_amdgcn_mfma_f32_16x16x32_bf16(a[kt], b, acc, 0, 0, 0);
        }
        float bv = bias ? bias[c] : 0.f;
        if constexpr (FUSE) {
            float wa = w2[c], wb = w2[64 + c];
#pragma unroll
            for (int reg = 0; reg < 4; reg++) {
                float v = fmaxf(acc[reg] + bv, 0.f);   // y1 with bias+relu
                p0[reg] = fmaf(v, wa, p0[reg]);
                p1[reg] = fmaf(v, wb, p1[reg]);
            }
        } else {
#pragma unroll
            for (int reg = 0; reg < 4; reg++) {
                int orow = r0 + q * 4 + reg;   // C/D: col=lane&15, row=quad*4+reg
                if (orow < NN) {
                    float v = acc[reg] + bv;
                    if (do_relu) v = fmaxf(v, 0.f);
                    outh[(size_t)orow * NC + c] = f2b(v);
                }
            }
        }
    }
    if constexpr (FUSE) {
#pragma unroll
        for (int off = 1; off < 16; off <<= 1) {
#pragma unroll
            for (int r = 0; r < 4; r++) {
                p0[r] += __shfl_xor(p0[r], off);
                p1[r] += __shfl_xor(p1[r], off);
            }
        }
        if (ln == 0) {
            float ba = b2v[0], bb = b2v[1];
#pragma unroll
            for (int reg = 0; reg < 4; reg++) {
                int orow = r0 + q * 4 + reg;
                if (orow < NN)
                    ((float2*)out2f)[orow] = make_float2(p0[reg] + ba, p1[reg] + bb);
            }
        }
    }
}

// ---- fused gather segment-reduce + self-loop + BN + ReLU -----------------
// one wave per node; lanes split 32/32 over 2 edges (uint2 = 4 ch/lane);
// 4B packed meta via nontemporal load, shfl broadcast, depth-8 pipeline.
__global__ __launch_bounds__(256) void k_aggr(const uint2* __restrict__ tH2,
        const unsigned* __restrict__ ewp, const int* __restrict__ offs,
        const int* __restrict__ cnt, const float* __restrict__ dinv,
        const float* __restrict__ bnA, const float* __restrict__ bnB,
        uint2* __restrict__ hout) {
    int wave = threadIdx.x >> 6, lane = threadIdx.x & 63;
    int node = blockIdx.x * 4 + wave;
    if (node >= NN) return;
    int base = offs[node], ne = cnt[node];
    float dd = dinv[node];
    int half = lane >> 5, li = lane & 31;
    uint2 sv = tH2[(size_t)node * 32 + li];
    float ws = half ? 0.f : dd;                // self = virtual edge, half 0
    float4 acc;
    acc.x = lo16(sv.x) * ws; acc.y = hi16(sv.x) * ws;
    acc.z = lo16(sv.y) * ws; acc.w = hi16(sv.y) * ws;
    for (int k0 = 0; k0 < ne; k0 += 64) {
        int idx = k0 + lane;
        unsigned m = idx < ne ? __builtin_nontemporal_load(&ewp[base + idx]) : 0u;
        int c2 = ne - k0 < 64 ? ne - k0 : 64;
        for (int kk = 0; kk < c2; kk += 16) {
            uint2 vv[8]; float wj[8];
#pragma unroll
            for (int j = 0; j < 8; j++) {
                int e = kk + 2 * j + half;
                unsigned mm = (unsigned)__shfl((int)m, e);
                int s = (int)(mm >> 15);
                wj[j] = __uint_as_float((mm & 0x7fffu) << 16);
                vv[j] = tH2[(size_t)s * 32 + li];
            }
#pragma unroll
            for (int j = 0; j < 8; j++) {
                acc.x = fmaf(lo16(vv[j].x), wj[j], acc.x);
                acc.y = fmaf(hi16(vv[j].x), wj[j], acc.y);
                acc.z = fmaf(lo16(vv[j].y), wj[j], acc.z);
                acc.w = fmaf(hi16(vv[j].y), wj[j], acc.w);
            }
        }
    }
    acc.x += __shfl_xor(acc.x, 32);
    acc.y += __shfl_xor(acc.y, 32);
    acc.z += __shfl_xor(acc.z, 32);
    acc.w += __shfl_xor(acc.w, 32);
    if (half == 0) {
        float4 Av = ((const float4*)bnA)[li];
        float4 Bv = ((const float4*)bnB)[li];
        float r0 = fmaxf(fmaf(acc.x * dd, Av.x, Bv.x), 0.f);
        float r1 = fmaxf(fmaf(acc.y * dd, Av.y, Bv.y), 0.f);
        float r2 = fmaxf(fmaf(acc.z * dd, Av.z, Bv.z), 0.f);
        float r3 = fmaxf(fmaf(acc.w * dd, Av.w, Bv.w), 0.f);
        unsigned long long v64 =
            ((unsigned long long)pack2(r2, r3) << 32) | pack2(r0, r1);
        __builtin_nontemporal_store(v64,
            (unsigned long long*)&hout[(size_t)node * 32 + li]);
    }
}

// ---- graph pooling: 1 wave per 32-node chunk, run-flush atomics ----------
#define PN 32
__global__ __launch_bounds__(64) void k_pool(const unsigned* __restrict__ hb,
        const int* __restrict__ batch, float* __restrict__ gsum,
        float* __restrict__ gcnt, const int* __restrict__ flag) {
    int lane = threadIdx.x;
    int f = *flag;
    int s0 = blockIdx.x * PN;
    int e0 = s0 + PN < NN ? s0 + PN : NN;
    int cur = geti(batch, s0, f);
    float a0 = 0.f, a1 = 0.f, cn = 0.f;
    for (int n = s0; n < e0; n++) {
        int g = geti(batch, n, f);
        if (g != cur) {                        // wave-uniform branch
            atomicAdd(&gsum[cur * HH + 2 * lane], a0);
            atomicAdd(&gsum[cur * HH + 2 * lane + 1], a1);
            if (lane == 0) atomicAdd(&gcnt[cur], cn);
            a0 = a1 = cn = 0.f; cur = g;
        }
        unsigned v = hb[(size_t)n * 64 + lane];
        a0 += lo16(v); a1 += hi16(v); cn += 1.f;
    }
    atomicAdd(&gsum[cur * HH + 2 * lane], a0);
    atomicAdd(&gsum[cur * HH + 2 * lane + 1], a1);
    if (lane == 0) atomicAdd(&gcnt[cur], cn);
}

// ---- graph head: one block per graph -------------------------------------
__global__ __launch_bounds__(64) void k_ghead(const float* __restrict__ gsum,
        const float* __restrict__ gcnt, const float* __restrict__ w1,
        const float* __restrict__ b1, const float* __restrict__ w2,
        const float* __restrict__ b2v, float* __restrict__ out) {
    __shared__ float emb[HH];
    int g = blockIdx.x, lane = threadIdx.x;
    float cn = gcnt[g];
    cn = cn > 1.f ? cn : 1.f;
    float inv = 1.f / cn;
    emb[lane] = gsum[g * HH + lane] * inv;
    emb[lane + 64] = gsum[g * HH + 64 + lane] * inv;
    __syncthreads();
    float acc = b1[lane];
    for (int k = 0; k < HH; k++) acc = fmaf(emb[k], w1[lane * HH + k], acc);
    float y = fmaxf(acc, 0.f);
    float v0 = y * w2[lane];
    float v1 = y * w2[64 + lane];
#pragma unroll
    for (int off = 32; off; off >>= 1) {
        v0 += __shfl_xor(v0, off);
        v1 += __shfl_xor(v1, off);
    }
    if (lane == 0) {
        out[(size_t)NN * 2 + g * 2]     = v0 + b2v[0];
        out[(size_t)NN * 2 + g * 2 + 1] = v1 + b2v[1];
    }
}

extern "C" void kernel_launch(void* const* d_in, const int* in_sizes, int n_in,
                              void* d_out, int out_size, void* d_ws, size_t ws_size,
                              hipStream_t stream) {
    const float* x      = (const float*)d_in[0];
    const int*   ei     = (const int*)d_in[1];
    const int*   batch  = (const int*)d_in[2];
    const float* conv_w = (const float*)d_in[3];
    const float* conv_b = (const float*)d_in[4];
    const float* bn_g   = (const float*)d_in[5];
    const float* bn_b   = (const float*)d_in[6];
    const float* bn_m   = (const float*)d_in[7];
    const float* bn_v   = (const float*)d_in[8];
    const float* nw1    = (const float*)d_in[9];
    const float* nb1    = (const float*)d_in[10];
    const float* nw2    = (const float*)d_in[11];
    const float* nb2    = (const float*)d_in[12];
    const float* gw1    = (const float*)d_in[13];
    const float* gb1    = (const float*)d_in[14];
    const float* gw2    = (const float*)d_in[15];
    const float* gb2    = (const float*)d_in[16];
    float* out = (float*)d_out;

    char* ws = (char*)d_ws;
    size_t off = 0;
    auto alloc = [&](size_t bytes) -> void* {
        void* p = ws + off;
        off += (bytes + 255) & ~(size_t)255;
        return p;
    };
    unsigned short* hb   = (unsigned short*)alloc((size_t)NN * HH * 2); // bf16 h
    unsigned short* tb   = (unsigned short*)alloc((size_t)NN * HH * 2); // bf16 t
    unsigned* slab   = (unsigned*)alloc((size_t)NT * CAP * 4);  // 9.6 MB
    unsigned* ewp    = (unsigned*)alloc((size_t)NT * CAP * 4);  // 9.6 MB
    int*      cnt    = (int*)     alloc((size_t)(NN + NT) * 4); // cnt + tcur
    int*      tcur   = cnt + NN;
    int*      offs   = (int*)     alloc((size_t)NN * 4);
    float*    dinv   = (float*)   alloc((size_t)NN * 4);
    float*    bnA    = (float*)   alloc((size_t)LL * HH * 4);
    float*    bnB    = (float*)   alloc((size_t)LL * HH * 4);
    float*    gsum   = (float*)   alloc((size_t)GG * HH * 4);
    float*    gcnt   = (float*)   alloc((size_t)GG * 4);
    unsigned short* cwB = (unsigned short*)alloc((size_t)LL * HH * HH * 2);
    unsigned short* n1B = (unsigned short*)alloc((size_t)64 * HH * 2);
    int*      flag   = (int*)     alloc(256);

    // CSR build: single partition pass -> per-tile sort (direct ewp emit)
    hipMemsetAsync(cnt, 0, (size_t)(NN + NT) * 4, stream);
    k_part<<<(EE + 4095) / 4096, 1024, 0, stream>>>(ei, cnt, tcur, slab, flag);
    k_csr<<<NT, 1024, 0, stream>>>(slab, tcur, cnt, ewp, offs, dinv);
    k_prep<<<(LL * HH * HH + 255) / 256, 256, 0, stream>>>(conv_w, nw1, cwB, n1B,
            bnA, bnB, conv_b, bn_g, bn_b, bn_m, bn_v, gsum, gcnt);

    // 3 GCN layers: MFMA gemm (h -> bf16 t), fused aggr+BN+ReLU (t -> bf16 h)
    k_gemm<float, HH, false><<<(NN + 63) / 64, 256, 0, stream>>>(
        x, cwB, nullptr, tb, 0, nullptr, nullptr, nullptr);
    k_aggr<<<(NN + 3) / 4, 256, 0, stream>>>((const uint2*)tb, ewp, offs, cnt,
                                             dinv, bnA, bnB, (uint2*)hb);
    for (int l = 1; l < LL; l++) {
        k_gemm<unsigned short, HH, false><<<(NN + 63) / 64, 256, 0, stream>>>(
            hb, cwB + (size_t)l * HH * HH, nullptr, tb, 0, nullptr, nullptr, nullptr);
        k_aggr<<<(NN + 3) / 4, 256, 0, stream>>>((const uint2*)tb, ewp, offs, cnt,
                                                 dinv, bnA + l * HH, bnB + l * HH,
                                                 (uint2*)hb);
    }

    // node head fully fused: y2 = relu(h@nw1^T+b1)@nw2^T+b2 in one kernel
    k_gemm<unsigned short, 64, true><<<(NN + 63) / 64, 256, 0, stream>>>(
        hb, n1B, nb1, nullptr, 1, nw2, nb2, out);

    // graph head
    k_pool<<<(NN + PN - 1) / PN, 64, 0, stream>>>((const unsigned*)hb, batch,
                                                  gsum, gcnt, flag);
    k_ghead<<<GG, 64, 0, stream>>>(gsum, gcnt, gw1, gb1, gw2, gb2, out);
}

// Round 10
// 504.299 us; speedup vs baseline: 1.0937x; 1.0787x over previous
//
#include <hip/hip_runtime.h>
#include <hip/hip_bf16.h>

#define NN 100000
#define EE 1600000
#define HH 128
#define GG 64
#define LL 3
#define BN_EPS 1e-5f
#define NT 391              // ceil(NN/256): 256-node tiles; also ceil(EE/4096)
#define CHW 392             // lbu row width (NT+1)
#define CAP 6144            // per-tile csr slab capacity (mean 4092, +32 sigma)

typedef __hip_bfloat16 bf16;
typedef __attribute__((ext_vector_type(8))) short short8;
typedef __attribute__((ext_vector_type(4))) float floatx4;

__device__ __forceinline__ float lo16(unsigned v) { return __uint_as_float(v << 16); }
__device__ __forceinline__ float hi16(unsigned v) { return __uint_as_float(v & 0xffff0000u); }
__device__ __forceinline__ unsigned short f2b(float v) {
    bf16 h = __float2bfloat16(v);
    return *(unsigned short*)&h;
}
__device__ __forceinline__ unsigned pack2(float a, float b) {
    return (unsigned)f2b(a) | ((unsigned)f2b(b) << 16);
}
__device__ __forceinline__ int geti(const int* __restrict__ p, int i, int f) {
    return f ? p[2 * i] : p[i];
}

// ---- pass 1: block-local tile sort, COALESCED chunk flush (no atomics) ---
// also folds the one-shot prep (weight casts, BN fold, pool init) into the
// spare thread indices, and publishes the int-width flag.
__global__ __launch_bounds__(1024) void k_part(const int* __restrict__ ei,
        unsigned* __restrict__ chunk, unsigned short* __restrict__ lbu,
        int* __restrict__ flag,
        const float* __restrict__ conv_w, const float* __restrict__ nw1,
        unsigned short* __restrict__ cwB, unsigned short* __restrict__ n1B,
        float* __restrict__ bnA, float* __restrict__ bnB,
        const float* __restrict__ conv_b, const float* __restrict__ g,
        const float* __restrict__ be, const float* __restrict__ mn,
        const float* __restrict__ vr, float* __restrict__ gsum,
        float* __restrict__ gcnt) {
    __shared__ int lcnt[NT];
    __shared__ int sd[512];
    __shared__ unsigned short lbs[CHW];
    __shared__ unsigned sorted[4096];
    int t = threadIdx.x;
    int e0 = blockIdx.x * 4096;
    // int64 layout <=> odd int32 slots all zero over a 64-edge probe
    int probe = ei[2 * (e0 + (t & 63)) + 1];
    int f = __any(probe != 0) ? 0 : 1;
    if (blockIdx.x == 0 && t == 0) *flag = f;
    // one-shot prep, spread across the grid (grid covers 400K > all arrays)
    int gi = blockIdx.x * 1024 + t;
    if (gi < LL * HH * HH) cwB[gi] = f2b(conv_w[gi]);
    if (gi < 64 * HH) n1B[gi] = f2b(nw1[gi]);
    if (gi < LL * HH) {
        float A = g[gi] * rsqrtf(vr[gi] + BN_EPS);
        bnA[gi] = A;
        bnB[gi] = (conv_b[gi] - mn[gi]) * A + be[gi];
    }
    if (gi < GG * HH) gsum[gi] = 0.f;
    if (gi < GG) gcnt[gi] = 0.f;
    int nume = EE - e0 < 4096 ? EE - e0 : 4096;
    for (int i = t; i < NT; i += 1024) lcnt[i] = 0;
    __syncthreads();
    unsigned pk[4]; int ml[4], mt[4];
#pragma unroll
    for (int i = 0; i < 4; i++) {
        int li = i * 1024 + t;
        if (li < nume) {
            int e = e0 + li;
            int src = geti(ei, e, f), dst = geti(ei, EE + e, f);
            mt[i] = dst >> 8;
            pk[i] = ((unsigned)src << 8) | (unsigned)(dst & 255);
            ml[i] = atomicAdd(&lcnt[mt[i]], 1);
        }
    }
    __syncthreads();
    int own = 0;
    if (t < 512) {
        own = t < NT ? lcnt[t] : 0;
        sd[t] = own;
    }
    __syncthreads();
    for (int off = 1; off < 512; off <<= 1) {
        int y = 0;
        if (t < 512 && t >= off) y = sd[t - off];
        __syncthreads();
        if (t < 512) sd[t] += y;
        __syncthreads();
    }
    if (t < NT) lbs[t] = (unsigned short)(sd[t] - own);
    if (t == 0) lbs[NT] = (unsigned short)nume;
    __syncthreads();
#pragma unroll
    for (int i = 0; i < 4; i++) {
        int li = i * 1024 + t;
        if (li < nume) sorted[(int)lbs[mt[i]] + ml[i]] = pk[i];
    }
    if (t < CHW) lbu[blockIdx.x * CHW + t] = lbs[t];
    __syncthreads();
    for (int idx = t; idx < nume; idx += 1024)
        __builtin_nontemporal_store(sorted[idx], &chunk[e0 + idx]);
}

// ---- pass 2: per-tile CSR; degree from hist (free); coalesced flush ------
__global__ __launch_bounds__(1024) void k_csr(const unsigned* __restrict__ chunk,
        const unsigned short* __restrict__ lbu, unsigned* __restrict__ csr,
        int* __restrict__ offs, int* __restrict__ cnt, float* __restrict__ dinv,
        int* __restrict__ tne) {
    __shared__ unsigned stage[CAP];
    __shared__ unsigned outb[CAP];
    __shared__ int sd[512];
    __shared__ int hist[256], exs[256], cur[256];
    int T = blockIdx.x, t = threadIdx.x;
    int st = 0, rl = 0;
    if (t < NT) {
        int s0 = lbu[t * CHW + T];
        int s1 = lbu[t * CHW + T + 1];
        st = t * 4096 + s0;
        rl = s1 - s0;
    }
    if (t < 512) sd[t] = rl;
    __syncthreads();
    for (int off = 1; off < 512; off <<= 1) {
        int y = 0;
        if (t < 512 && t >= off) y = sd[t - off];
        __syncthreads();
        if (t < 512) sd[t] += y;
        __syncthreads();
    }
    int ne = sd[511];
    if (ne > CAP) ne = CAP;                    // never in practice
    int so = t < NT ? sd[t] - rl : 0;
    if (t < 256) hist[t] = 0;
    __syncthreads();
    if (t < NT) {
        for (int j = 0; j < rl; j++) {
            int p = so + j;
            if (p < CAP)
                stage[p] = __builtin_nontemporal_load(&chunk[st + j]);
        }
    }
    __syncthreads();
    for (int i = t; i < ne; i += 1024)
        atomicAdd(&hist[stage[i] & 255u], 1);
    __syncthreads();
    int c = 0;
    if (t < 256) {
        c = hist[t];
        exs[t] = c;
    }
    __syncthreads();
    for (int off = 1; off < 256; off <<= 1) {
        int a = 0;
        if (t < 256 && t >= off) a = exs[t - off];
        __syncthreads();
        if (t < 256) exs[t] += a;
        __syncthreads();
    }
    if (t < 256) {
        int ex = exs[t] - c;
        cur[t] = ex;
        int node = T * 256 + t;
        if (node < NN) {
            offs[node] = T * CAP + ex;
            cnt[node] = c;
            dinv[node] = rsqrtf(1.0f + (float)c);
        }
    }
    if (t == 0) tne[T] = ne;
    __syncthreads();
    for (int i = t; i < ne; i += 1024) {
        unsigned p = stage[i];
        int q = atomicAdd(&cur[p & 255u], 1);
        outb[q] = p >> 8;                      // pure src
    }
    __syncthreads();
    for (int i = t; i < ne; i += 1024)
        csr[(size_t)T * CAP + i] = outb[i];
}

// ---- pass 3: pack edge meta (dinv now fully known; 400KB L2 gather) ------
__global__ __launch_bounds__(1024) void k_wpack(const unsigned* __restrict__ csr,
        const float* __restrict__ dinv, unsigned* __restrict__ ewp,
        const int* __restrict__ tne) {
    int T = blockIdx.x, t = threadIdx.x;
    int ne = tne[T];
    for (int i = t; i < ne; i += 1024) {
        unsigned s = csr[(size_t)T * CAP + i];
        ewp[(size_t)T * CAP + i] = (s << 15) | ((unsigned)f2b(dinv[s]) & 0x7fffu);
    }
}

// ---- MFMA bf16 GEMM: out[r][c] = sum_k in[r][k]*W[c][k] (+bias, relu) ----
// FUSE: fold y2 = y1 @ w2^T + b2 (64->2) into the epilogue (node head).
template<typename AT, int NC, bool FUSE>
__global__ __launch_bounds__(256) void k_gemm(const AT* __restrict__ in,
        const unsigned short* __restrict__ Wb, const float* __restrict__ bias,
        unsigned short* __restrict__ outh, int do_relu,
        const float* __restrict__ w2, const float* __restrict__ b2v,
        float* __restrict__ out2f) {
    int wave = threadIdx.x >> 6, lane = threadIdx.x & 63;
    int ln = lane & 15, q = lane >> 4;
    int r0 = blockIdx.x * 64 + wave * 16;
    int row = r0 + ln;
    int rr = row < NN ? row : NN - 1;          // clamp loads, guard stores
    short8 a[4];
    if constexpr (sizeof(AT) == 2) {
        const short8* ap = (const short8*)(in + (size_t)rr * HH);
#pragma unroll
        for (int kt = 0; kt < 4; kt++) a[kt] = ap[kt * 4 + q];
    } else {
        const float4* ap = (const float4*)(in + (size_t)rr * HH);
#pragma unroll
        for (int kt = 0; kt < 4; kt++) {
            float4 f0 = ap[(kt * 4 + q) * 2];
            float4 f1 = ap[(kt * 4 + q) * 2 + 1];
            a[kt][0] = (short)f2b(f0.x); a[kt][1] = (short)f2b(f0.y);
            a[kt][2] = (short)f2b(f0.z); a[kt][3] = (short)f2b(f0.w);
            a[kt][4] = (short)f2b(f1.x); a[kt][5] = (short)f2b(f1.y);
            a[kt][6] = (short)f2b(f1.z); a[kt][7] = (short)f2b(f1.w);
        }
    }
    float p0[4], p1[4];
    if constexpr (FUSE) {
#pragma unroll
        for (int r = 0; r < 4; r++) { p0[r] = 0.f; p1[r] = 0.f; }
    }
#pragma unroll
    for (int ct = 0; ct < NC / 16; ct++) {
        int c = ct * 16 + ln;
        const short8* bp = (const short8*)(Wb + (size_t)c * HH);
        floatx4 acc = {0.f, 0.f, 0.f, 0.f};
#pragma unroll
        for (int kt = 0; kt < 4; kt++) {
            short8 b = bp[kt * 4 + q];
            acc = __builtin_amdgcn_mfma_f32_16x16x32_bf16(a[kt], b, acc, 0, 0, 0);
        }
        float bv = bias ? bias[c] : 0.f;
        if constexpr (FUSE) {
            float wa = w2[c], wb = w2[64 + c];
#pragma unroll
            for (int reg = 0; reg < 4; reg++) {
                float v = fmaxf(acc[reg] + bv, 0.f);   // y1 with bias+relu
                p0[reg] = fmaf(v, wa, p0[reg]);
                p1[reg] = fmaf(v, wb, p1[reg]);
            }
        } else {
#pragma unroll
            for (int reg = 0; reg < 4; reg++) {
                int orow = r0 + q * 4 + reg;   // C/D: col=lane&15, row=quad*4+reg
                if (orow < NN) {
                    float v = acc[reg] + bv;
                    if (do_relu) v = fmaxf(v, 0.f);
                    outh[(size_t)orow * NC + c] = f2b(v);
                }
            }
        }
    }
    if constexpr (FUSE) {
#pragma unroll
        for (int off = 1; off < 16; off <<= 1) {
#pragma unroll
            for (int r = 0; r < 4; r++) {
                p0[r] += __shfl_xor(p0[r], off);
                p1[r] += __shfl_xor(p1[r], off);
            }
        }
        if (ln == 0) {
            float ba = b2v[0], bb = b2v[1];
#pragma unroll
            for (int reg = 0; reg < 4; reg++) {
                int orow = r0 + q * 4 + reg;
                if (orow < NN)
                    ((float2*)out2f)[orow] = make_float2(p0[reg] + ba, p1[reg] + bb);
            }
        }
    }
}

// ---- fused gather segment-reduce + self-loop + BN + ReLU -----------------
// one wave per node; lanes split 32/32 over 2 edges (uint2 = 4 ch/lane);
// 4B packed meta via nontemporal load, shfl broadcast, depth-8 pipeline.
__global__ __launch_bounds__(256) void k_aggr(const uint2* __restrict__ tH2,
        const unsigned* __restrict__ ewp, const int* __restrict__ offs,
        const int* __restrict__ cnt, const float* __restrict__ dinv,
        const float* __restrict__ bnA, const float* __restrict__ bnB,
        uint2* __restrict__ hout) {
    int wave = threadIdx.x >> 6, lane = threadIdx.x & 63;
    int node = blockIdx.x * 4 + wave;
    if (node >= NN) return;
    int base = offs[node], ne = cnt[node];
    float dd = dinv[node];
    int half = lane >> 5, li = lane & 31;
    uint2 sv = tH2[(size_t)node * 32 + li];
    float ws = half ? 0.f : dd;                // self = virtual edge, half 0
    float4 acc;
    acc.x = lo16(sv.x) * ws; acc.y = hi16(sv.x) * ws;
    acc.z = lo16(sv.y) * ws; acc.w = hi16(sv.y) * ws;
    for (int k0 = 0; k0 < ne; k0 += 64) {
        int idx = k0 + lane;
        unsigned m = idx < ne ? __builtin_nontemporal_load(&ewp[base + idx]) : 0u;
        int c2 = ne - k0 < 64 ? ne - k0 : 64;
        for (int kk = 0; kk < c2; kk += 16) {
            uint2 vv[8]; float wj[8];
#pragma unroll
            for (int j = 0; j < 8; j++) {
                int e = kk + 2 * j + half;
                unsigned mm = (unsigned)__shfl((int)m, e);
                int s = (int)(mm >> 15);
                wj[j] = __uint_as_float((mm & 0x7fffu) << 16);
                vv[j] = tH2[(size_t)s * 32 + li];
            }
#pragma unroll
            for (int j = 0; j < 8; j++) {
                acc.x = fmaf(lo16(vv[j].x), wj[j], acc.x);
                acc.y = fmaf(hi16(vv[j].x), wj[j], acc.y);
                acc.z = fmaf(lo16(vv[j].y), wj[j], acc.z);
                acc.w = fmaf(hi16(vv[j].y), wj[j], acc.w);
            }
        }
    }
    acc.x += __shfl_xor(acc.x, 32);
    acc.y += __shfl_xor(acc.y, 32);
    acc.z += __shfl_xor(acc.z, 32);
    acc.w += __shfl_xor(acc.w, 32);
    if (half == 0) {
        float4 Av = ((const float4*)bnA)[li];
        float4 Bv = ((const float4*)bnB)[li];
        float r0 = fmaxf(fmaf(acc.x * dd, Av.x, Bv.x), 0.f);
        float r1 = fmaxf(fmaf(acc.y * dd, Av.y, Bv.y), 0.f);
        float r2 = fmaxf(fmaf(acc.z * dd, Av.z, Bv.z), 0.f);
        float r3 = fmaxf(fmaf(acc.w * dd, Av.w, Bv.w), 0.f);
        unsigned long long v64 =
            ((unsigned long long)pack2(r2, r3) << 32) | pack2(r0, r1);
        __builtin_nontemporal_store(v64,
            (unsigned long long*)&hout[(size_t)node * 32 + li]);
    }
}

// ---- graph pooling: 1 wave per 32-node chunk, run-flush atomics ----------
#define PN 32
__global__ __launch_bounds__(64) void k_pool(const unsigned* __restrict__ hb,
        const int* __restrict__ batch, float* __restrict__ gsum,
        float* __restrict__ gcnt, const int* __restrict__ flag) {
    int lane = threadIdx.x;
    int f = *flag;
    int s0 = blockIdx.x * PN;
    int e0 = s0 + PN < NN ? s0 + PN : NN;
    int cur = geti(batch, s0, f);
    float a0 = 0.f, a1 = 0.f, cn = 0.f;
    for (int n = s0; n < e0; n++) {
        int g = geti(batch, n, f);
        if (g != cur) {                        // wave-uniform branch
            atomicAdd(&gsum[cur * HH + 2 * lane], a0);
            atomicAdd(&gsum[cur * HH + 2 * lane + 1], a1);
            if (lane == 0) atomicAdd(&gcnt[cur], cn);
            a0 = a1 = cn = 0.f; cur = g;
        }
        unsigned v = hb[(size_t)n * 64 + lane];
        a0 += lo16(v); a1 += hi16(v); cn += 1.f;
    }
    atomicAdd(&gsum[cur * HH + 2 * lane], a0);
    atomicAdd(&gsum[cur * HH + 2 * lane + 1], a1);
    if (lane == 0) atomicAdd(&gcnt[cur], cn);
}

// ---- graph head: one block per graph -------------------------------------
__global__ __launch_bounds__(64) void k_ghead(const float* __restrict__ gsum,
        const float* __restrict__ gcnt, const float* __restrict__ w1,
        const float* __restrict__ b1, const float* __restrict__ w2,
        const float* __restrict__ b2v, float* __restrict__ out) {
    __shared__ float emb[HH];
    int g = blockIdx.x, lane = threadIdx.x;
    float cn = gcnt[g];
    cn = cn > 1.f ? cn : 1.f;
    float inv = 1.f / cn;
    emb[lane] = gsum[g * HH + lane] * inv;
    emb[lane + 64] = gsum[g * HH + 64 + lane] * inv;
    __syncthreads();
    float acc = b1[lane];
    for (int k = 0; k < HH; k++) acc = fmaf(emb[k], w1[lane * HH + k], acc);
    float y = fmaxf(acc, 0.f);
    float v0 = y * w2[lane];
    float v1 = y * w2[64 + lane];
#pragma unroll
    for (int off = 32; off; off >>= 1) {
        v0 += __shfl_xor(v0, off);
        v1 += __shfl_xor(v1, off);
    }
    if (lane == 0) {
        out[(size_t)NN * 2 + g * 2]     = v0 + b2v[0];
        out[(size_t)NN * 2 + g * 2 + 1] = v1 + b2v[1];
    }
}

extern "C" void kernel_launch(void* const* d_in, const int* in_sizes, int n_in,
                              void* d_out, int out_size, void* d_ws, size_t ws_size,
                              hipStream_t stream) {
    const float* x      = (const float*)d_in[0];
    const int*   ei     = (const int*)d_in[1];
    const int*   batch  = (const int*)d_in[2];
    const float* conv_w = (const float*)d_in[3];
    const float* conv_b = (const float*)d_in[4];
    const float* bn_g   = (const float*)d_in[5];
    const float* bn_b   = (const float*)d_in[6];
    const float* bn_m   = (const float*)d_in[7];
    const float* bn_v   = (const float*)d_in[8];
    const float* nw1    = (const float*)d_in[9];
    const float* nb1    = (const float*)d_in[10];
    const float* nw2    = (const float*)d_in[11];
    const float* nb2    = (const float*)d_in[12];
    const float* gw1    = (const float*)d_in[13];
    const float* gb1    = (const float*)d_in[14];
    const float* gw2    = (const float*)d_in[15];
    const float* gb2    = (const float*)d_in[16];
    float* out = (float*)d_out;

    char* ws = (char*)d_ws;
    size_t off = 0;
    auto alloc = [&](size_t bytes) -> void* {
        void* p = ws + off;
        off += (bytes + 255) & ~(size_t)255;
        return p;
    };
    unsigned short* hb   = (unsigned short*)alloc((size_t)NN * HH * 2); // bf16 h
    unsigned short* tb   = (unsigned short*)alloc((size_t)NN * HH * 2); // bf16 t
    unsigned* chunk  = (unsigned*)alloc((size_t)EE * 4);        // 6.4 MB
    unsigned* csr    = (unsigned*)alloc((size_t)NT * CAP * 4);  // 9.6 MB
    unsigned* ewp    = (unsigned*)alloc((size_t)NT * CAP * 4);  // 9.6 MB
    unsigned short* lbu = (unsigned short*)alloc((size_t)NT * CHW * 2); // 306 KB
    int*      offs   = (int*)     alloc((size_t)NN * 4);
    int*      cnt    = (int*)     alloc((size_t)NN * 4);
    float*    dinv   = (float*)   alloc((size_t)NN * 4);
    int*      tne    = (int*)     alloc((size_t)NT * 4);
    float*    bnA    = (float*)   alloc((size_t)LL * HH * 4);
    float*    bnB    = (float*)   alloc((size_t)LL * HH * 4);
    float*    gsum   = (float*)   alloc((size_t)GG * HH * 4);
    float*    gcnt   = (float*)   alloc((size_t)GG * 4);
    unsigned short* cwB = (unsigned short*)alloc((size_t)LL * HH * HH * 2);
    unsigned short* n1B = (unsigned short*)alloc((size_t)64 * HH * 2);
    int*      flag   = (int*)     alloc(256);

    // CSR build: coalesced 2-pass (no global atomics) + meta pack
    k_part<<<NT, 1024, 0, stream>>>(ei, chunk, lbu, flag, conv_w, nw1, cwB, n1B,
            bnA, bnB, conv_b, bn_g, bn_b, bn_m, bn_v, gsum, gcnt);
    k_csr<<<NT, 1024, 0, stream>>>(chunk, lbu, csr, offs, cnt, dinv, tne);
    k_wpack<<<NT, 1024, 0, stream>>>(csr, dinv, ewp, tne);

    // 3 GCN layers: MFMA gemm (h -> bf16 t), fused aggr+BN+ReLU (t -> bf16 h)
    k_gemm<float, HH, false><<<(NN + 63) / 64, 256, 0, stream>>>(
        x, cwB, nullptr, tb, 0, nullptr, nullptr, nullptr);
    k_aggr<<<(NN + 3) / 4, 256, 0, stream>>>((const uint2*)tb, ewp, offs, cnt,
                                             dinv, bnA, bnB, (uint2*)hb);
    for (int l = 1; l < LL; l++) {
        k_gemm<unsigned short, HH, false><<<(NN + 63) / 64, 256, 0, stream>>>(
            hb, cwB + (size_t)l * HH * HH, nullptr, tb, 0, nullptr, nullptr, nullptr);
        k_aggr<<<(NN + 3) / 4, 256, 0, stream>>>((const uint2*)tb, ewp, offs, cnt,
                                                 dinv, bnA + l * HH, bnB + l * HH,
                                                 (uint2*)hb);
    }

    // node head fully fused: y2 = relu(h@nw1^T+b1)@nw2^T+b2 in one kernel
    k_gemm<unsigned short, 64, true><<<(NN + 63) / 64, 256, 0, stream>>>(
        hb, n1B, nb1, nullptr, 1, nw2, nb2, out);

    // graph head
    k_pool<<<(NN + PN - 1) / PN, 64, 0, stream>>>((const unsigned*)hb, batch,
                                                  gsum, gcnt, flag);
    k_ghead<<<GG, 64, 0, stream>>>(gsum, gcnt, gw1, gb1, gw2, gb2, out);
}